// Round 17
// baseline (623.306 us; speedup 1.0000x reference)
//
#include <hip/hip_runtime.h>
#include <hip/hip_bf16.h>
#include <math.h>

typedef __attribute__((ext_vector_type(8))) short short8;
typedef __attribute__((ext_vector_type(4))) float f32x4;
typedef __attribute__((ext_vector_type(16))) float f32x16;
typedef __attribute__((ext_vector_type(4))) unsigned short u16x4;
typedef __attribute__((ext_vector_type(8))) unsigned short u16x8;
typedef __attribute__((ext_vector_type(4))) unsigned int u32x4;
typedef __attribute__((ext_vector_type(2))) int i32x2;
typedef unsigned short u16;
typedef unsigned int u32;

#define DM 2048
#define SQ 2048
#define NB 4
#define NH 16
#define DKH 128
#define KT 64
#define NT (SQ / KT)
#define LD2 (2 * DM)
#define NROW (NB * SQ)
#define NX8 (NROW * DM / 8)
#define NW8 (DM * DM / 8)
#define QSCALE (0.08838834764831845f * 1.4426950408889634f)

__device__ __forceinline__ u16 f2bf(float f) {
  unsigned u = __float_as_uint(f);
  u += 0x7fffu + ((u >> 16) & 1u);
  return (u16)(u >> 16);
}

__device__ __forceinline__ u32 cvtpk(float lo, float hi) {
  u32 r;
  asm("v_cvt_pk_bf16_f32 %0, %1, %2" : "=v"(r) : "v"(lo), "v"(hi));
  return r;
}

__device__ __forceinline__ void gload16(const u16* g, u16* lds) {
  __builtin_amdgcn_global_load_lds(
      (const __attribute__((address_space(1))) unsigned int*)g,
      (__attribute__((address_space(3))) unsigned int*)lds, 16, 0, 0);
}

// P-layout (fragment-order HBM layout, 256-row tiles, BK=64, nkt = K/64)
__device__ __forceinline__ int paddr16(int r, int k, int nkt) {
  const int cid = (((r >> 8) * nkt + (k >> 6)) << 5) | (((r >> 7) & 1) << 4) |
                  (((r >> 5) & 3) << 2) | ((k >> 4) & 3);
  return (cid << 9) + (((r & 31) | (((k >> 3) & 1) << 3 << 2)) << 3) + (k & 7);
}

__device__ __forceinline__ void pinv(int idx, int nkt, int& r, int& k) {
  const int e8 = idx & 63;
  const int cid = idx >> 6;
  const int kt = (cid >> 5) % nkt;
  const int rt = (cid >> 5) / nkt;
  r = (rt << 8) + (((cid >> 4) & 1) << 7) + (((cid >> 2) & 3) << 5) + (e8 & 31);
  k = (kt << 6) + ((cid & 3) << 4) + ((e8 >> 5) << 3);
}

// Merged cvt: x + 4 weights -> P-layout bf16, single launch.
// Segments are multiples of 256 so each block is branch-uniform.
__global__ void cvt_all(const float* __restrict__ x,
                        const float* __restrict__ w0, const float* __restrict__ w1,
                        const float* __restrict__ w2, const float* __restrict__ w3,
                        u16* __restrict__ xb, u16* __restrict__ wqb,
                        u16* __restrict__ wob) {
  const int gid = blockIdx.x * 256 + threadIdx.x;
  const float* src;
  u16* dst;
  int idx;
  if (gid < NX8) {
    src = x; dst = xb; idx = gid;
  } else {
    const int t = gid - NX8;
    const int sel = t / NW8;
    idx = t - sel * NW8;
    src = sel == 0 ? w0 : sel == 1 ? w1 : sel == 2 ? w2 : w3;
    dst = (sel < 3) ? (wqb + (size_t)sel * DM * DM) : wob;
  }
  int r, k;
  pinv(idx, 32, r, k);
  const float4 v0 = *(const float4*)(src + (size_t)r * DM + k);
  const float4 v1 = *(const float4*)(src + (size_t)r * DM + k + 4);
  u16x8 o;
  o[0] = f2bf(v0.x); o[1] = f2bf(v0.y); o[2] = f2bf(v0.z); o[3] = f2bf(v0.w);
  o[4] = f2bf(v1.x); o[5] = f2bf(v1.y); o[6] = f2bf(v1.z); o[7] = f2bf(v1.w);
  *(u16x8*)(dst + (size_t)idx * 8) = o;
}

// ---------------- 256x256 pipelined GEMM, P-layout, 4 barriers/K-tile ---------
// (round-11/16 proven structure.) MODE 0: fused QKV -> Q,K row-major to QK
// buffer [M][4096]; V TRANSPOSED to VT[2048][M]. MODE 1: C f32 [M][N], bias bq.

#define STG_A(T, HALF)                                                       \
  do {                                                                       \
    _Pragma("unroll") for (int uu = 0; uu < 2; ++uu) {                       \
      const int j_ = w * 2 + uu;                                             \
      gload16(As + ((((T) * 32 + (HALF) * 16 + j_) << 9) + l * 8),           \
              &smA[((T) & 1) * 16384 + ((HALF) * 16 + j_) * 512]);           \
    }                                                                        \
  } while (0)

#define STG_B(T, HALF)                                                       \
  do {                                                                       \
    _Pragma("unroll") for (int uu = 0; uu < 2; ++uu) {                       \
      const int j_ = w * 2 + uu;                                             \
      gload16(Bs + ((((T) * 32 + (HALF) * 16 + j_) << 9) + l * 8),           \
              &smB[((T) & 1) * 16384 + ((HALF) * 16 + j_) * 512]);           \
    }                                                                        \
  } while (0)

#define LDA(QM)                                                            \
  do {                                                                     \
    const int rb_ = wr * 4 + (QM) * 2;                                     \
    const u16* p_ = &smA[bi * 16384 + rb_ * 2048 + l * 8];                 \
    _Pragma("unroll") for (int s = 0; s < 4; ++s) {                        \
      af[0][s] = *(const short8*)&p_[s * 512];                             \
      af[1][s] = *(const short8*)&p_[2048 + s * 512];                      \
    }                                                                      \
  } while (0)

#define LDB(QN)                                                            \
  do {                                                                     \
    const int rb_ = wc * 2 + (QN);                                         \
    const u16* p_ = &smB[bi * 16384 + rb_ * 2048 + l * 8];                 \
    _Pragma("unroll") for (int s = 0; s < 4; ++s)                          \
      bf[QN][s] = *(const short8*)&p_[s * 512];                            \
  } while (0)

#define MFMA_Q(QM, QN)                                                             \
  __builtin_amdgcn_s_setprio(1);                                                   \
  _Pragma("unroll") for (int s = 0; s < 4; ++s) {                                  \
    acc[(QM) * 2][(QN)] = __builtin_amdgcn_mfma_f32_32x32x16_bf16(                 \
        af[0][s], bf[QN][s], acc[(QM) * 2][(QN)], 0, 0, 0);                        \
    acc[(QM) * 2 + 1][(QN)] = __builtin_amdgcn_mfma_f32_32x32x16_bf16(             \
        af[1][s], bf[QN][s], acc[(QM) * 2 + 1][(QN)], 0, 0, 0);                    \
  }                                                                                \
  __builtin_amdgcn_s_setprio(0);

template <int MODE>
__global__ __launch_bounds__(512, 2) void gemm8p(
    const u16* __restrict__ A, const u16* __restrict__ B,
    const float* __restrict__ bq, const float* __restrict__ bk,
    const float* __restrict__ bvp, void* __restrict__ Cout,
    void* __restrict__ Cout2, int M, int N, int K) {
  __shared__ u16 smA[2 * 16384];  // [buf][32 chunks of 1KB in fragment order]
  __shared__ u16 smB[2 * 16384];
  const int tid = threadIdx.x;
  const int w = tid >> 6, l = tid & 63;
  const int c5 = l & 31, hi = l >> 5;
  const int wr = w >> 2, wc = w & 3;

  int flat = blockIdx.x + (int)gridDim.x * (int)blockIdx.y;
  const int nwg = (int)(gridDim.x * gridDim.y);
  flat = (flat & 7) * (nwg >> 3) + (flat >> 3);
  const int m0 = (flat / (int)gridDim.x) * 256, n0 = (flat % (int)gridDim.x) * 256;

  const int NSTEP = K / 64;
  f32x16 acc[4][2] = {};

  const u16* As = A + (size_t)(m0 >> 8) * NSTEP * 16384;
  const u16* Bs = B + (size_t)(n0 >> 8) * NSTEP * 16384;

  STG_A(0, 0); STG_A(0, 1); STG_B(0, 0); STG_B(0, 1);
  STG_B(1, 0); STG_A(1, 0);
  asm volatile("s_waitcnt vmcnt(4)" ::: "memory");
  __builtin_amdgcn_s_barrier();

  short8 af[2][4], bf[2][4];
  for (int t = 0; t < NSTEP; ++t) {
    const int bi = t & 1;
    LDA(0); LDB(0);
    if (t + 1 < NSTEP) STG_B(t + 1, 1);
    MFMA_Q(0, 0);
    __builtin_amdgcn_s_barrier();
    LDB(1);
    if (t + 1 < NSTEP) STG_A(t + 1, 1);
    MFMA_Q(0, 1);
    __builtin_amdgcn_s_barrier();
    LDA(1);
    if (t + 2 < NSTEP) STG_B(t + 2, 0);
    MFMA_Q(1, 1);
    __builtin_amdgcn_s_barrier();
    if (t + 2 < NSTEP) STG_A(t + 2, 0);
    MFMA_Q(1, 0);
    if (t + 2 < NSTEP)
      asm volatile("s_waitcnt vmcnt(4)" ::: "memory");
    else if (t + 1 < NSTEP)
      asm volatile("s_waitcnt vmcnt(0)" ::: "memory");
    __builtin_amdgcn_s_barrier();
  }

#pragma unroll
  for (int nf = 0; nf < 2; ++nf) {
    const int col = n0 + wc * 64 + nf * 32 + c5;
    if (MODE == 0) {
      const int seg = col >> 11;
      const float* bp = seg == 0 ? bq : (seg == 1 ? bk : bvp);
      const float bval = bp[col & (DM - 1)];
      const float os = (seg == 0) ? QSCALE : 1.0f;
      if (seg < 2) {
#pragma unroll
        for (int mf = 0; mf < 4; ++mf)
#pragma unroll
          for (int r = 0; r < 16; ++r) {
            const int row = m0 + wr * 128 + mf * 32 + (r & 3) + 8 * (r >> 2) + 4 * hi;
            ((u16*)Cout)[(size_t)row * LD2 + col] = f2bf((acc[mf][nf][r] + bval) * os);
          }
      } else {
        u16* vbase = (u16*)Cout2 + (size_t)(col - 2 * DM) * NROW;
#pragma unroll
        for (int mf = 0; mf < 4; ++mf) {
          const int row0 = m0 + wr * 128 + mf * 32 + 4 * hi;
#pragma unroll
          for (int g2 = 0; g2 < 4; ++g2) {
            u16x4 pk;
#pragma unroll
            for (int j = 0; j < 4; ++j)
              pk[j] = f2bf(acc[mf][nf][g2 * 4 + j] + bval);
            *(u16x4*)(vbase + row0 + 8 * g2) = pk;
          }
        }
      }
    } else {
      const float bval = bq[col];
#pragma unroll
      for (int mf = 0; mf < 4; ++mf)
#pragma unroll
        for (int r = 0; r < 16; ++r) {
          const int row = m0 + wr * 128 + mf * 32 + (r & 3) + 8 * (r >> 2) + 4 * hi;
          ((float*)Cout)[(size_t)row * N + col] = acc[mf][nf][r] + bval;
        }
    }
  }
}

// Flash attention, 4-wave (256-thread) blocks, 128 q-rows, KV tiles of 64.
// K double-buffered (32KB), V single-buffered from VT via gload_lds (16KB)
// -> 49.7KB LDS -> 3 blocks/CU (12 waves, 3/SIMD) for cross-block TLP.
// Counted-vmcnt pipeline (issue order K(t+1) < V(t+1) < K(t+2), in-order):
//   vmcnt(8) before QK confirms K(t); vmcnt(4)+barrier#1 before PV confirms
//   ALL waves' V(t) (closes cross-wave race); barrier#2 after PV frees smV;
//   V(t+1) issued after barrier#2. Last tile peels to vmcnt(4)/vmcnt(0).
__global__ __launch_bounds__(256) void attn(
    const u16* __restrict__ QK, const u16* __restrict__ VT, u16* __restrict__ O) {
  __shared__ u16 smK[2 * 8192];   // [buf][kv 64][256B rows, 16x16B slots, ^row&15]
  __shared__ u16 smV[8192];       // [d 128][64 kv] linear (source-swizzled)
  __shared__ float alScr[4 * 32];

  const u16* Qp = QK;
  const u16* Kp = QK + DM;

  const int tid = threadIdx.x;
  const int w = tid >> 6, l = tid & 63;
  const int c5 = l & 31, hi = l >> 5;

  // XCD swizzle over 1024 blocks (16 q-tiles x 16 h x 4 b)
  int flat = blockIdx.x + ((int)blockIdx.y << 4) + ((int)blockIdx.z << 8);
  flat = (flat & 7) * 128 + (flat >> 3);
  const int qt = flat & 15, h = (flat >> 4) & 15, b = flat >> 8;

  const int q0 = qt * 128 + w * 32;
  const size_t rowb = (size_t)b * SQ;
  const int hoff = h * DKH;

  short8 qf[8];
#pragma unroll
  for (int ds = 0; ds < 8; ++ds)
    qf[ds] = *(const short8*)&Qp[(rowb + q0 + c5) * LD2 + hoff + ds * 16 + hi * 8];

  f32x16 o[4] = {};
  float mrow = -1e30f, lsum = 0.f;

  // per-lane V^T staging source base (chunk u adds u*8*NROW; tile adds kv0)
  const u16* vsrc = VT + (size_t)(hoff + (l >> 3)) * NROW + rowb + ((l & 7) ^ (l >> 3)) * 8;

  // ---- prologue: K(0) -> smK[0], V(0) -> smV; full drain; barrier ----
  {
#pragma unroll
    for (int uu = 0; uu < 4; ++uu) {
      const int u = w * 4 + uu;
      const int row = u * 4 + (l >> 4);
      const int col16 = (l & 15) ^ (row & 15);
      gload16(&Kp[(rowb + row) * LD2 + hoff + col16 * 8], &smK[u * 512]);
    }
#pragma unroll
    for (int uu = 0; uu < 4; ++uu) {
      const int u = w * 4 + uu;
      gload16(vsrc + (size_t)u * 8 * NROW, &smV[u * 512]);
    }
  }
  asm volatile("s_waitcnt vmcnt(0)" ::: "memory");
  __builtin_amdgcn_s_barrier();

  int buf = 0;
  for (int t = 0; t < NT; ++t) {
    const int nb = buf ^ 1;
    // ---- a: issue K(t+1) -> smK[nb] ----
    if (t + 1 < NT) {
      const size_t kvr = rowb + (size_t)(t + 1) * KT;
#pragma unroll
      for (int uu = 0; uu < 4; ++uu) {
        const int u = w * 4 + uu;
        const int row = u * 4 + (l >> 4);
        const int col16 = (l & 15) ^ (row & 15);
        gload16(&Kp[(kvr + row) * LD2 + hoff + col16 * 8], &smK[nb * 8192 + u * 512]);
      }
      asm volatile("s_waitcnt vmcnt(8)" ::: "memory");  // K(t) confirmed
    } else {
      asm volatile("s_waitcnt vmcnt(4)" ::: "memory");  // K(t) confirmed (only V(t) newer)
    }
    __builtin_amdgcn_sched_barrier(0);

    // ---- S^T = mfma(K, Q) ----
    f32x16 s[2] = {};
    __builtin_amdgcn_s_setprio(1);
#pragma unroll
    for (int ds = 0; ds < 8; ++ds) {
#pragma unroll
      for (int ni = 0; ni < 2; ++ni) {
        const int row = ni * 32 + c5;
        const short8 kf = *(const short8*)&smK[buf * 8192 + row * 128 + (((ds << 1) | hi) ^ (row & 15)) * 8];
        s[ni] = __builtin_amdgcn_mfma_f32_32x32x16_bf16(kf, qf[ds], s[ni], 0, 0, 0);
      }
    }
    __builtin_amdgcn_s_setprio(0);

    // ---- tree max + deferred-max online softmax ----
    float mt[16];
#pragma unroll
    for (int i = 0; i < 16; ++i) mt[i] = fmaxf(s[0][i], s[1][i]);
#pragma unroll
    for (int st = 8; st >= 1; st >>= 1)
#pragma unroll
      for (int i = 0; i < st; ++i) mt[i] = fmaxf(mt[i], mt[i + st]);
    i32x2 sw = __builtin_amdgcn_permlane32_swap(__float_as_int(mt[0]), __float_as_int(mt[0]), false, false);
    const float gmax = fmaxf(__int_as_float(sw.x), __int_as_float(sw.y));

    if (__any(gmax > mrow + 10.0f)) {
      const float mn = fmaxf(mrow, gmax);
      const float al = exp2f(mrow - mn);
      mrow = mn;
      lsum *= al;
      alScr[w * 32 + c5] = al;
#pragma unroll
      for (int r = 0; r < 16; ++r) {
        const float av = alScr[w * 32 + (r & 3) + 8 * (r >> 2) + 4 * hi];
#pragma unroll
        for (int dg = 0; dg < 4; ++dg) o[dg][r] *= av;
      }
    }

    float ps0 = 0.f, ps1 = 0.f;
#pragma unroll
    for (int i = 0; i < 16; ++i) {
      const float p0 = exp2f(s[0][i] - mrow);
      const float p1 = exp2f(s[1][i] - mrow);
      s[0][i] = p0; s[1][i] = p1;
      ps0 += p0; ps1 += p1;
    }
    lsum += ps0 + ps1;

    // ---- confirm ALL waves' V(t) before PV: own vmcnt + barrier#1 ----
    if (t + 1 < NT)
      asm volatile("s_waitcnt vmcnt(4)" ::: "memory");  // V(t) done; K(t+1) outstanding
    else
      asm volatile("s_waitcnt vmcnt(0)" ::: "memory");
    __builtin_amdgcn_s_barrier();  // barrier #1
    __builtin_amdgcn_sched_barrier(0);

    // ---- P -> A-frags (cvt_pk + permlane32_swap), then O += P V ----
    __builtin_amdgcn_s_setprio(1);
#pragma unroll
    for (int ks = 0; ks < 4; ++ks) {
      const int b0_ = (ks & 1) * 8;
      const int ni = ks >> 1;
      const u32 A0 = cvtpk(s[ni][b0_ + 0], s[ni][b0_ + 1]);
      const u32 A1 = cvtpk(s[ni][b0_ + 4], s[ni][b0_ + 5]);
      const u32 B0 = cvtpk(s[ni][b0_ + 2], s[ni][b0_ + 3]);
      const u32 B1 = cvtpk(s[ni][b0_ + 6], s[ni][b0_ + 7]);
      const i32x2 r0 = __builtin_amdgcn_permlane32_swap((int)A0, (int)A1, false, false);
      const i32x2 r1 = __builtin_amdgcn_permlane32_swap((int)B0, (int)B1, false, false);
      u32x4 paw;
      paw.x = (u32)r0.x; paw.y = (u32)r1.x; paw.z = (u32)r0.y; paw.w = (u32)r1.y;
      const short8 pa = *(const short8*)&paw;
#pragma unroll
      for (int dg = 0; dg < 4; ++dg) {
        const int rowd = dg * 32 + c5;
        const short8 vf = *(const short8*)&smV[rowd * 64 + (((ks * 2 + hi) ^ (rowd & 7))) * 8];
        o[dg] = __builtin_amdgcn_mfma_f32_32x32x16_bf16(pa, vf, o[dg], 0, 0, 0);
      }
    }
    __builtin_amdgcn_s_setprio(0);

    // ---- barrier #2: smV free; then issue V(t+1) ----
    __builtin_amdgcn_s_barrier();
    if (t + 1 < NT) {
      const int kv1 = (t + 1) * KT;
#pragma unroll
      for (int uu = 0; uu < 4; ++uu) {
        const int u = w * 4 + uu;
        gload16(vsrc + (size_t)u * 8 * NROW + kv1, &smV[u * 512]);
      }
    }
    buf = nb;
  }

  // ---- finalize ----
  {
    const i32x2 sl = __builtin_amdgcn_permlane32_swap(__float_as_int(lsum), __float_as_int(lsum), false, false);
    const float tot = __int_as_float(sl.x) + __int_as_float(sl.y);
    alScr[w * 32 + c5] = 1.0f / tot;
  }
#pragma unroll
  for (int r = 0; r < 16; ++r) {
    const int qloc = (r & 3) + 8 * (r >> 2) + 4 * hi;
    const float inv = alScr[w * 32 + qloc];
    const int rowg = (int)rowb + q0 + qloc;
#pragma unroll
    for (int dg = 0; dg < 4; ++dg)
      O[paddr16(rowg, hoff + dg * 32 + c5, 32)] = f2bf(o[dg][r] * inv);
  }
}

extern "C" void kernel_launch(void* const* d_in, const int* in_sizes, int n_in,
                              void* d_out, int out_size, void* d_ws, size_t ws_size,
                              hipStream_t stream) {
  const float* x    = (const float*)d_in[0];
  const float* wq_w = (const float*)d_in[1];
  const float* wq_b = (const float*)d_in[2];
  const float* wk_w = (const float*)d_in[3];
  const float* wk_b = (const float*)d_in[4];
  const float* wv_w = (const float*)d_in[5];
  const float* wv_b = (const float*)d_in[6];
  const float* wo_w = (const float*)d_in[7];
  const float* wo_b = (const float*)d_in[8];
  float* out = (float*)d_out;

  u16* p = (u16*)d_ws;
  u16* xb  = p; p += (size_t)NROW * DM;          // x in P-layout, reused as ctx (P)
  u16* wqb = p; p += (size_t)3 * DM * DM;        // wq|wk|wv stacked, P-layout
  u16* wob = p; p += (size_t)DM * DM;            // wo, P-layout
  u16* QKb = p; p += (size_t)NROW * LD2;         // Q|K row-major [8192][4096]
  u16* VTb = p; p += (size_t)DM * NROW;          // V transposed [2048][8192]
  u16* ctx = xb;

  cvt_all<<<dim3((NX8 + 4 * NW8) / 256), dim3(256), 0, stream>>>(
      x, wq_w, wk_w, wv_w, wo_w, xb, wqb, wob);

  // fused QKV projection: [8192][2048] @ [6144][2048]^T -> QK row-major + VT
  dim3 gg3(3 * DM / 256, NROW / 256);
  gemm8p<0><<<gg3, dim3(512), 0, stream>>>(xb, wqb, wq_b, wk_b, wv_b, QKb, VTb,
                                           NROW, 3 * DM, DM);

  attn<<<dim3(SQ / 128, NH, NB), dim3(256), 0, stream>>>(QKb, VTb, ctx);

  dim3 ggo(DM / 256, NROW / 256);
  gemm8p<1><<<ggo, dim3(512), 0, stream>>>(ctx, wob, wo_b, nullptr, nullptr, out,
                                           nullptr, NROW, DM, DM);
}

// Round 18
// 541.200 us; speedup vs baseline: 1.1517x; 1.1517x over previous
//
#include <hip/hip_runtime.h>
#include <hip/hip_bf16.h>
#include <math.h>

typedef __attribute__((ext_vector_type(8))) short short8;
typedef __attribute__((ext_vector_type(4))) float f32x4;
typedef __attribute__((ext_vector_type(16))) float f32x16;
typedef __attribute__((ext_vector_type(4))) unsigned short u16x4;
typedef __attribute__((ext_vector_type(8))) unsigned short u16x8;
typedef __attribute__((ext_vector_type(4))) unsigned int u32x4;
typedef __attribute__((ext_vector_type(2))) int i32x2;
typedef unsigned short u16;
typedef unsigned int u32;

#define DM 2048
#define SQ 2048
#define NB 4
#define NH 16
#define DKH 128
#define KT 64
#define NT (SQ / KT)
#define LD3 (3 * DM)
#define NROW (NB * SQ)
#define NX8 (NROW * DM / 8)
#define NW8 (DM * DM / 8)
#define QSCALE (0.08838834764831845f * 1.4426950408889634f)

__device__ __forceinline__ u16 f2bf(float f) {
  unsigned u = __float_as_uint(f);
  u += 0x7fffu + ((u >> 16) & 1u);
  return (u16)(u >> 16);
}

__device__ __forceinline__ u32 cvtpk(float lo, float hi) {
  u32 r;
  asm("v_cvt_pk_bf16_f32 %0, %1, %2" : "=v"(r) : "v"(lo), "v"(hi));
  return r;
}

__device__ __forceinline__ void gload16(const u16* g, u16* lds) {
  __builtin_amdgcn_global_load_lds(
      (const __attribute__((address_space(1))) unsigned int*)g,
      (__attribute__((address_space(3))) unsigned int*)lds, 16, 0, 0);
}

// P-layout (fragment-order HBM layout, 256-row tiles, BK=64, nkt = K/64)
__device__ __forceinline__ int paddr16(int r, int k, int nkt) {
  const int cid = (((r >> 8) * nkt + (k >> 6)) << 5) | (((r >> 7) & 1) << 4) |
                  (((r >> 5) & 3) << 2) | ((k >> 4) & 3);
  return (cid << 9) + (((r & 31) | (((k >> 3) & 1) << 3 << 2)) << 3) + (k & 7);
}

__device__ __forceinline__ void pinv(int idx, int nkt, int& r, int& k) {
  const int e8 = idx & 63;
  const int cid = idx >> 6;
  const int kt = (cid >> 5) % nkt;
  const int rt = (cid >> 5) / nkt;
  r = (rt << 8) + (((cid >> 4) & 1) << 7) + (((cid >> 2) & 3) << 5) + (e8 & 31);
  k = (kt << 6) + ((cid & 3) << 4) + ((e8 >> 5) << 3);
}

// Merged cvt: x + 4 weights -> P-layout bf16, single launch.
// Segment boundaries are multiples of 256 so each block is branch-uniform.
__global__ void cvt_all(const float* __restrict__ x,
                        const float* __restrict__ w0, const float* __restrict__ w1,
                        const float* __restrict__ w2, const float* __restrict__ w3,
                        u16* __restrict__ xb, u16* __restrict__ wqb,
                        u16* __restrict__ wob) {
  const int gid = blockIdx.x * 256 + threadIdx.x;
  const float* src;
  u16* dst;
  int idx;
  if (gid < NX8) {
    src = x; dst = xb; idx = gid;
  } else {
    const int t = gid - NX8;
    const int sel = t / NW8;
    idx = t - sel * NW8;
    src = sel == 0 ? w0 : sel == 1 ? w1 : sel == 2 ? w2 : w3;
    dst = (sel < 3) ? (wqb + (size_t)sel * DM * DM) : wob;
  }
  int r, k;
  pinv(idx, 32, r, k);
  const float4 v0 = *(const float4*)(src + (size_t)r * DM + k);
  const float4 v1 = *(const float4*)(src + (size_t)r * DM + k + 4);
  u16x8 o;
  o[0] = f2bf(v0.x); o[1] = f2bf(v0.y); o[2] = f2bf(v0.z); o[3] = f2bf(v0.w);
  o[4] = f2bf(v1.x); o[5] = f2bf(v1.y); o[6] = f2bf(v1.z); o[7] = f2bf(v1.w);
  *(u16x8*)(dst + (size_t)idx * 8) = o;
}

// ---------------- 256x256 pipelined GEMM, P-layout, 4 barriers/K-tile ---------
// (round-11 proven structure: one barrier per phase, no forced lgkmcnt,
//  counted vmcnt(4) at tile end, fragment-order LDS => 0 bank conflicts)
// MODE 0: fused QKV -> C bf16 row-major [M][6144], bias/scale per segment.
// MODE 1: single -> C f32 row-major [M][N], bias = bq.

#define STG_A(T, HALF)                                                       \
  do {                                                                       \
    _Pragma("unroll") for (int uu = 0; uu < 2; ++uu) {                       \
      const int j_ = w * 2 + uu;                                             \
      gload16(As + ((((T) * 32 + (HALF) * 16 + j_) << 9) + l * 8),           \
              &smA[((T) & 1) * 16384 + ((HALF) * 16 + j_) * 512]);           \
    }                                                                        \
  } while (0)

#define STG_B(T, HALF)                                                       \
  do {                                                                       \
    _Pragma("unroll") for (int uu = 0; uu < 2; ++uu) {                       \
      const int j_ = w * 2 + uu;                                             \
      gload16(Bs + ((((T) * 32 + (HALF) * 16 + j_) << 9) + l * 8),           \
              &smB[((T) & 1) * 16384 + ((HALF) * 16 + j_) * 512]);           \
    }                                                                        \
  } while (0)

#define LDA(QM)                                                            \
  do {                                                                     \
    const int rb_ = wr * 4 + (QM) * 2;                                     \
    const u16* p_ = &smA[bi * 16384 + rb_ * 2048 + l * 8];                 \
    _Pragma("unroll") for (int s = 0; s < 4; ++s) {                        \
      af[0][s] = *(const short8*)&p_[s * 512];                             \
      af[1][s] = *(const short8*)&p_[2048 + s * 512];                      \
    }                                                                      \
  } while (0)

#define LDB(QN)                                                            \
  do {                                                                     \
    const int rb_ = wc * 2 + (QN);                                         \
    const u16* p_ = &smB[bi * 16384 + rb_ * 2048 + l * 8];                 \
    _Pragma("unroll") for (int s = 0; s < 4; ++s)                          \
      bf[QN][s] = *(const short8*)&p_[s * 512];                            \
  } while (0)

#define MFMA_Q(QM, QN)                                                             \
  __builtin_amdgcn_s_setprio(1);                                                   \
  _Pragma("unroll") for (int s = 0; s < 4; ++s) {                                  \
    acc[(QM) * 2][(QN)] = __builtin_amdgcn_mfma_f32_32x32x16_bf16(                 \
        af[0][s], bf[QN][s], acc[(QM) * 2][(QN)], 0, 0, 0);                        \
    acc[(QM) * 2 + 1][(QN)] = __builtin_amdgcn_mfma_f32_32x32x16_bf16(             \
        af[1][s], bf[QN][s], acc[(QM) * 2 + 1][(QN)], 0, 0, 0);                    \
  }                                                                                \
  __builtin_amdgcn_s_setprio(0);

template <int MODE>
__global__ __launch_bounds__(512, 2) void gemm8p(
    const u16* __restrict__ A, const u16* __restrict__ B,
    const float* __restrict__ bq, const float* __restrict__ bk,
    const float* __restrict__ bvp, void* __restrict__ Cout,
    int M, int N, int K) {
  __shared__ u16 smA[2 * 16384];  // [buf][32 chunks of 1KB in fragment order]
  __shared__ u16 smB[2 * 16384];
  const int tid = threadIdx.x;
  const int w = tid >> 6, l = tid & 63;
  const int c5 = l & 31, hi = l >> 5;
  const int wr = w >> 2, wc = w & 3;

  // XCD-aware swizzle (nwg % 8 == 0 for all our launches)
  int flat = blockIdx.x + (int)gridDim.x * (int)blockIdx.y;
  const int nwg = (int)(gridDim.x * gridDim.y);
  flat = (flat & 7) * (nwg >> 3) + (flat >> 3);
  const int m0 = (flat / (int)gridDim.x) * 256, n0 = (flat % (int)gridDim.x) * 256;

  const int NSTEP = K / 64;
  f32x16 acc[4][2] = {};

  const u16* As = A + (size_t)(m0 >> 8) * NSTEP * 16384;
  const u16* Bs = B + (size_t)(n0 >> 8) * NSTEP * 16384;

  STG_A(0, 0); STG_A(0, 1); STG_B(0, 0); STG_B(0, 1);
  STG_B(1, 0); STG_A(1, 0);
  asm volatile("s_waitcnt vmcnt(4)" ::: "memory");
  __builtin_amdgcn_s_barrier();

  short8 af[2][4], bf[2][4];
  for (int t = 0; t < NSTEP; ++t) {
    const int bi = t & 1;
    // ---- P0 ----
    LDA(0); LDB(0);
    if (t + 1 < NSTEP) STG_B(t + 1, 1);
    MFMA_Q(0, 0);
    __builtin_amdgcn_s_barrier();
    // ---- P1 ----
    LDB(1);
    if (t + 1 < NSTEP) STG_A(t + 1, 1);
    MFMA_Q(0, 1);
    __builtin_amdgcn_s_barrier();
    // ---- P2 ----
    LDA(1);
    if (t + 2 < NSTEP) STG_B(t + 2, 0);
    MFMA_Q(1, 1);
    __builtin_amdgcn_s_barrier();
    // ---- P3 ----
    if (t + 2 < NSTEP) STG_A(t + 2, 0);
    MFMA_Q(1, 0);
    if (t + 2 < NSTEP)
      asm volatile("s_waitcnt vmcnt(4)" ::: "memory");
    else if (t + 1 < NSTEP)
      asm volatile("s_waitcnt vmcnt(0)" ::: "memory");
    __builtin_amdgcn_s_barrier();
  }

#pragma unroll
  for (int nf = 0; nf < 2; ++nf) {
    const int col = n0 + wc * 64 + nf * 32 + c5;
    float bval, os;
    if (MODE == 0) {
      const int seg = col >> 11;
      const float* bp = seg == 0 ? bq : (seg == 1 ? bk : bvp);
      bval = bp[col & (DM - 1)];
      os = (seg == 0) ? QSCALE : 1.0f;
    } else {
      bval = bq[col];
      os = 1.0f;
    }
#pragma unroll
    for (int mf = 0; mf < 4; ++mf) {
#pragma unroll
      for (int r = 0; r < 16; ++r) {
        const int row = m0 + wr * 128 + mf * 32 + (r & 3) + 8 * (r >> 2) + 4 * hi;
        const float v = (acc[mf][nf][r] + bval) * os;
        if (MODE == 1)
          ((float*)Cout)[(size_t)row * N + col] = v;
        else
          ((u16*)Cout)[(size_t)row * N + col] = f2bf(v);
      }
    }
  }
}

// Flash attention (round-11 proven version): 8 waves x 32 q, KV tiles of 64,
// K dbuf via gload_lds, V single-buffered write-late (2 barriers/tile),
// swapped QK^T (ds-outer) -> in-register softmax (tree max, cvt_pk +
// permlane32_swap). ctx out in P-layout. Measured: 0 bank conflicts.
__global__ __launch_bounds__(512, 2) void attn(
    const u16* __restrict__ QKV, u16* __restrict__ O) {
  __shared__ u16 smK[2 * 8192];
  __shared__ u16 smV[9216];
  __shared__ float alScr[8 * 32];

  const u16* Qp = QKV;
  const u16* Kp = QKV + DM;
  const u16* Vp = QKV + 2 * DM;

  const int tid = threadIdx.x;
  const int w = tid >> 6, l = tid & 63;
  const int c5 = l & 31, hi = l >> 5;

  int flat = blockIdx.x + ((int)blockIdx.y << 3) + ((int)blockIdx.z << 7);
  flat = (flat & 7) * 64 + (flat >> 3);
  const int qt = flat & 7, h = (flat >> 3) & 15, b = flat >> 7;

  const int q0 = qt * 256 + w * 32;
  const size_t rowb = (size_t)b * SQ;
  const int hoff = h * DKH;

  short8 qf[8];
#pragma unroll
  for (int ds = 0; ds < 8; ++ds)
    qf[ds] = *(const short8*)&Qp[(rowb + q0 + c5) * LD3 + hoff + ds * 16 + hi * 8];

  f32x16 o[4] = {};
  float mrow = -1e30f, lsum = 0.f;

  const int vdg = tid >> 5;
  const int kvp = (tid & 31) * 2;
  u16x8 va, vb;

  {
#pragma unroll
    for (int uu = 0; uu < 2; ++uu) {
      const int u = w * 2 + uu;
      const int row = u * 4 + (l >> 4);
      const int col16 = (l & 15) ^ (row & 15);
      gload16(&Kp[(rowb + row) * LD3 + hoff + col16 * 8], &smK[u * 512]);
    }
    const u16* vp = &Vp[(rowb + kvp) * LD3 + hoff + vdg * 8];
    va = *(const u16x8*)vp;
    vb = *(const u16x8*)(vp + LD3);
#pragma unroll
    for (int i = 0; i < 8; ++i) {
      const int d = vdg * 8 + i;
      *(u32*)&smV[d * 72 + kvp] = (u32)va[i] | ((u32)vb[i] << 16);
    }
  }
  __syncthreads();

  int buf = 0;
  for (int t = 0; t < NT; ++t) {
    const int nb = buf ^ 1;
    if (t + 1 < NT) {
      const size_t kvr = rowb + (size_t)(t + 1) * KT;
#pragma unroll
      for (int uu = 0; uu < 2; ++uu) {
        const int u = w * 2 + uu;
        const int row = u * 4 + (l >> 4);
        const int col16 = (l & 15) ^ (row & 15);
        gload16(&Kp[(kvr + row) * LD3 + hoff + col16 * 8], &smK[nb * 8192 + u * 512]);
      }
      const u16* vp = &Vp[(kvr + kvp) * LD3 + hoff + vdg * 8];
      va = *(const u16x8*)vp;
      vb = *(const u16x8*)(vp + LD3);
    }

    // ---- S^T = mfma(K, Q): ds-outer -> two interleaved acc chains ----
    f32x16 s[2] = {};
    __builtin_amdgcn_s_setprio(1);
#pragma unroll
    for (int ds = 0; ds < 8; ++ds) {
#pragma unroll
      for (int ni = 0; ni < 2; ++ni) {
        const int row = ni * 32 + c5;
        const short8 kf = *(const short8*)&smK[buf * 8192 + row * 128 + (((ds << 1) | hi) ^ (row & 15)) * 8];
        s[ni] = __builtin_amdgcn_mfma_f32_32x32x16_bf16(kf, qf[ds], s[ni], 0, 0, 0);
      }
    }
    __builtin_amdgcn_s_setprio(0);

    // ---- tree max (depth 5) ----
    float mt[16];
#pragma unroll
    for (int i = 0; i < 16; ++i) mt[i] = fmaxf(s[0][i], s[1][i]);
#pragma unroll
    for (int st = 8; st >= 1; st >>= 1)
#pragma unroll
      for (int i = 0; i < st; ++i) mt[i] = fmaxf(mt[i], mt[i + st]);
    i32x2 sw = __builtin_amdgcn_permlane32_swap(__float_as_int(mt[0]), __float_as_int(mt[0]), false, false);
    const float gmax = fmaxf(__int_as_float(sw.x), __int_as_float(sw.y));

    if (__any(gmax > mrow + 10.0f)) {
      const float mn = fmaxf(mrow, gmax);
      const float al = exp2f(mrow - mn);
      mrow = mn;
      lsum *= al;
      alScr[w * 32 + c5] = al;
#pragma unroll
      for (int r = 0; r < 16; ++r) {
        const float av = alScr[w * 32 + (r & 3) + 8 * (r >> 2) + 4 * hi];
#pragma unroll
        for (int dg = 0; dg < 4; ++dg) o[dg][r] *= av;
      }
    }

    float ps0 = 0.f, ps1 = 0.f;
#pragma unroll
    for (int i = 0; i < 16; ++i) {
      const float p0 = exp2f(s[0][i] - mrow);
      const float p1 = exp2f(s[1][i] - mrow);
      s[0][i] = p0; s[1][i] = p1;
      ps0 += p0; ps1 += p1;
    }
    lsum += ps0 + ps1;

    __builtin_amdgcn_s_setprio(1);
#pragma unroll
    for (int ks = 0; ks < 4; ++ks) {
      const int b0_ = (ks & 1) * 8;
      const int ni = ks >> 1;
      const u32 A0 = cvtpk(s[ni][b0_ + 0], s[ni][b0_ + 1]);
      const u32 A1 = cvtpk(s[ni][b0_ + 4], s[ni][b0_ + 5]);
      const u32 B0 = cvtpk(s[ni][b0_ + 2], s[ni][b0_ + 3]);
      const u32 B1 = cvtpk(s[ni][b0_ + 6], s[ni][b0_ + 7]);
      const i32x2 r0 = __builtin_amdgcn_permlane32_swap((int)A0, (int)A1, false, false);
      const i32x2 r1 = __builtin_amdgcn_permlane32_swap((int)B0, (int)B1, false, false);
      u32x4 paw;
      paw.x = (u32)r0.x; paw.y = (u32)r1.x; paw.z = (u32)r0.y; paw.w = (u32)r1.y;
      const short8 pa = *(const short8*)&paw;
#pragma unroll
      for (int dg = 0; dg < 4; ++dg) {
        const int rowd = dg * 32 + c5;
        const short8 vf = *(const short8*)&smV[rowd * 72 + ks * 16 + hi * 8];
        o[dg] = __builtin_amdgcn_mfma_f32_32x32x16_bf16(pa, vf, o[dg], 0, 0, 0);
      }
    }
    __builtin_amdgcn_s_setprio(0);

    __syncthreads();
    if (t + 1 < NT) {
#pragma unroll
      for (int i = 0; i < 8; ++i) {
        const int d = vdg * 8 + i;
        *(u32*)&smV[d * 72 + kvp] = (u32)va[i] | ((u32)vb[i] << 16);
      }
      __syncthreads();
    }
    buf = nb;
  }

  {
    const i32x2 sl = __builtin_amdgcn_permlane32_swap(__float_as_int(lsum), __float_as_int(lsum), false, false);
    const float tot = __int_as_float(sl.x) + __int_as_float(sl.y);
    alScr[w * 32 + c5] = 1.0f / tot;
  }
#pragma unroll
  for (int r = 0; r < 16; ++r) {
    const int qloc = (r & 3) + 8 * (r >> 2) + 4 * hi;
    const float inv = alScr[w * 32 + qloc];
    const int rowg = (int)rowb + q0 + qloc;
#pragma unroll
    for (int dg = 0; dg < 4; ++dg)
      O[paddr16(rowg, hoff + dg * 32 + c5, 32)] = f2bf(o[dg][r] * inv);
  }
}

extern "C" void kernel_launch(void* const* d_in, const int* in_sizes, int n_in,
                              void* d_out, int out_size, void* d_ws, size_t ws_size,
                              hipStream_t stream) {
  const float* x    = (const float*)d_in[0];
  const float* wq_w = (const float*)d_in[1];
  const float* wq_b = (const float*)d_in[2];
  const float* wk_w = (const float*)d_in[3];
  const float* wk_b = (const float*)d_in[4];
  const float* wv_w = (const float*)d_in[5];
  const float* wv_b = (const float*)d_in[6];
  const float* wo_w = (const float*)d_in[7];
  const float* wo_b = (const float*)d_in[8];
  float* out = (float*)d_out;

  u16* p = (u16*)d_ws;
  u16* xb  = p; p += (size_t)NROW * DM;          // x in P-layout, reused as ctx (P)
  u16* wqb = p; p += (size_t)3 * DM * DM;        // wq|wk|wv stacked, P-layout
  u16* wob = p; p += (size_t)DM * DM;            // wo, P-layout
  u16* QKV = p; p += (size_t)NROW * LD3;         // fused [8192][6144] row-major
  u16* ctx = xb;

  cvt_all<<<dim3((NX8 + 4 * NW8) / 256), dim3(256), 0, stream>>>(
      x, wq_w, wk_w, wv_w, wo_w, xb, wqb, wob);

  // fused QKV projection: [8192][2048] @ [6144][2048]^T -> [8192][6144]
  dim3 gg3(3 * DM / 256, NROW / 256);
  gemm8p<0><<<gg3, dim3(512), 0, stream>>>(xb, wqb, wq_b, wk_b, wv_b, QKV,
                                           NROW, 3 * DM, DM);

  attn<<<dim3(SQ / 256, NH, NB), dim3(512), 0, stream>>>(QKV, ctx);

  dim3 ggo(DM / 256, NROW / 256);
  gemm8p<1><<<ggo, dim3(512), 0, stream>>>(ctx, wob, wo_b, nullptr, nullptr, out,
                                           NROW, DM, DM);
}

// Round 20
// 537.733 us; speedup vs baseline: 1.1591x; 1.0064x over previous
//
#include <hip/hip_runtime.h>
#include <hip/hip_bf16.h>
#include <math.h>

typedef __attribute__((ext_vector_type(8))) short short8;
typedef __attribute__((ext_vector_type(4))) float f32x4;
typedef __attribute__((ext_vector_type(16))) float f32x16;
typedef __attribute__((ext_vector_type(4))) unsigned short u16x4;
typedef __attribute__((ext_vector_type(8))) unsigned short u16x8;
typedef __attribute__((ext_vector_type(4))) unsigned int u32x4;
typedef __attribute__((ext_vector_type(2))) int i32x2;
typedef unsigned short u16;
typedef unsigned int u32;

#define DM 2048
#define SQ 2048
#define NB 4
#define NH 16
#define DKH 128
#define KT 64
#define NT (SQ / KT)
#define LD3 (3 * DM)
#define NROW (NB * SQ)
#define NX8 (NROW * DM / 8)
#define NW8 (DM * DM / 8)
#define QSCALE (0.08838834764831845f * 1.4426950408889634f)

__device__ __forceinline__ u16 f2bf(float f) {
  unsigned u = __float_as_uint(f);
  u += 0x7fffu + ((u >> 16) & 1u);
  return (u16)(u >> 16);
}

__device__ __forceinline__ u32 cvtpk(float lo, float hi) {
  u32 r;
  asm("v_cvt_pk_bf16_f32 %0, %1, %2" : "=v"(r) : "v"(lo), "v"(hi));
  return r;
}

__device__ __forceinline__ void gload16(const u16* g, u16* lds) {
  __builtin_amdgcn_global_load_lds(
      (const __attribute__((address_space(1))) unsigned int*)g,
      (__attribute__((address_space(3))) unsigned int*)lds, 16, 0, 0);
}

// P-layout (fragment-order HBM layout, 256-row tiles, BK=64, nkt = K/64)
__device__ __forceinline__ int paddr16(int r, int k, int nkt) {
  const int cid = (((r >> 8) * nkt + (k >> 6)) << 5) | (((r >> 7) & 1) << 4) |
                  (((r >> 5) & 3) << 2) | ((k >> 4) & 3);
  return (cid << 9) + (((r & 31) | (((k >> 3) & 1) << 3 << 2)) << 3) + (k & 7);
}

__device__ __forceinline__ void pinv(int idx, int nkt, int& r, int& k) {
  const int e8 = idx & 63;
  const int cid = idx >> 6;
  const int kt = (cid >> 5) % nkt;
  const int rt = (cid >> 5) / nkt;
  r = (rt << 8) + (((cid >> 4) & 1) << 7) + (((cid >> 2) & 3) << 5) + (e8 & 31);
  k = (kt << 6) + ((cid & 3) << 4) + ((e8 >> 5) << 3);
}

// Merged cvt: x + 4 weights -> P-layout bf16, single launch.
__global__ void cvt_all(const float* __restrict__ x,
                        const float* __restrict__ w0, const float* __restrict__ w1,
                        const float* __restrict__ w2, const float* __restrict__ w3,
                        u16* __restrict__ xb, u16* __restrict__ wqb,
                        u16* __restrict__ wob) {
  const int gid = blockIdx.x * 256 + threadIdx.x;
  const float* src;
  u16* dst;
  int idx;
  if (gid < NX8) {
    src = x; dst = xb; idx = gid;
  } else {
    const int t = gid - NX8;
    const int sel = t / NW8;
    idx = t - sel * NW8;
    src = sel == 0 ? w0 : sel == 1 ? w1 : sel == 2 ? w2 : w3;
    dst = (sel < 3) ? (wqb + (size_t)sel * DM * DM) : wob;
  }
  int r, k;
  pinv(idx, 32, r, k);
  const float4 v0 = *(const float4*)(src + (size_t)r * DM + k);
  const float4 v1 = *(const float4*)(src + (size_t)r * DM + k + 4);
  u16x8 o;
  o[0] = f2bf(v0.x); o[1] = f2bf(v0.y); o[2] = f2bf(v0.z); o[3] = f2bf(v0.w);
  o[4] = f2bf(v1.x); o[5] = f2bf(v1.y); o[6] = f2bf(v1.z); o[7] = f2bf(v1.w);
  *(u16x8*)(dst + (size_t)idx * 8) = o;
}

// -------- 256x256 GEMM, P-layout, column-phases (2 barriers/K-tile) ---------
// 16 MFMA/phase as 4 independent acc chains. RACE-FIXED staging (r19 post-mortem:
// staged B-half0 overlapped P1's B-rb-odd reads):
//   P0 stages {A-half1, B-col1}(t+1) -> buf nb   (other buffer, always safe)
//   P1 stages {A-half0, B-col0}(t+2) -> buf bi   (A and B-col0 read ONLY in P0;
//                                                 disjoint from P1's B-col1 reads)
// B-col0 = rb even {0,2,4,6} (chunks (2*(c>>2))*4+(c&3)); B-col1 = rb odd.
// vmcnt ledger (P0_k=4, P1_k=4 loads, in-order): vmcnt(4) at P1-end leaves P1_t
// outstanding, confirming P0_t + P1_{t-1} = ALL of tile t+1 before its reads.
// P0-end: plain barrier (producers confirmed one barrier earlier).
// Fragment-order LDS: all ds accesses linear -> 0 bank conflicts.

#define STG_AH(T, HALF)                                                      \
  do {                                                                       \
    _Pragma("unroll") for (int uu = 0; uu < 2; ++uu) {                       \
      const int j_ = (HALF) * 16 + w * 2 + uu;                               \
      gload16(As + ((((T) * 32 + j_) << 9) + l * 8),                         \
              &smA[((T) & 1) * 16384 + j_ * 512]);                           \
    }                                                                        \
  } while (0)

#define STG_BC(T, COL)                                                       \
  do {                                                                       \
    _Pragma("unroll") for (int uu = 0; uu < 2; ++uu) {                       \
      const int c_ = w * 2 + uu;                                             \
      const int j_ = ((2 * (c_ >> 2) + (COL)) << 2) + (c_ & 3);              \
      gload16(Bs + ((((T) * 32 + j_) << 9) + l * 8),                         \
              &smB[((T) & 1) * 16384 + j_ * 512]);                           \
    }                                                                        \
  } while (0)

#define LDA_ALL                                                            \
  do {                                                                     \
    _Pragma("unroll") for (int q4 = 0; q4 < 4; ++q4) {                     \
      const u16* p_ = &smA[bi * 16384 + (wr * 4 + q4) * 2048 + l * 8];     \
      _Pragma("unroll") for (int s = 0; s < 4; ++s)                        \
        af[q4][s] = *(const short8*)&p_[s * 512];                          \
    }                                                                      \
  } while (0)

#define LDB(QN)                                                            \
  do {                                                                     \
    const u16* p_ = &smB[bi * 16384 + (wc * 2 + (QN)) * 2048 + l * 8];     \
    _Pragma("unroll") for (int s = 0; s < 4; ++s)                          \
      bf[s] = *(const short8*)&p_[s * 512];                                \
  } while (0)

#define MFMA_COL(QN)                                                               \
  __builtin_amdgcn_s_setprio(1);                                                   \
  _Pragma("unroll") for (int s = 0; s < 4; ++s)                                    \
    _Pragma("unroll") for (int q4 = 0; q4 < 4; ++q4)                               \
      acc[q4][(QN)] = __builtin_amdgcn_mfma_f32_32x32x16_bf16(                     \
          af[q4][s], bf[s], acc[q4][(QN)], 0, 0, 0);                               \
  __builtin_amdgcn_s_setprio(0);

#define VMW(N) asm volatile("s_waitcnt vmcnt(" #N ")" ::: "memory")

template <int MODE>
__global__ __launch_bounds__(512, 2) void gemm8p(
    const u16* __restrict__ A, const u16* __restrict__ B,
    const float* __restrict__ bq, const float* __restrict__ bk,
    const float* __restrict__ bvp, void* __restrict__ Cout,
    int M, int N, int K) {
  __shared__ u16 smA[2 * 16384];  // [buf][32 chunks of 1KB in fragment order]
  __shared__ u16 smB[2 * 16384];
  const int tid = threadIdx.x;
  const int w = tid >> 6, l = tid & 63;
  const int c5 = l & 31, hi = l >> 5;
  const int wr = w >> 2, wc = w & 3;

  // XCD-aware swizzle (nwg % 8 == 0 for all our launches)
  int flat = blockIdx.x + (int)gridDim.x * (int)blockIdx.y;
  const int nwg = (int)(gridDim.x * gridDim.y);
  flat = (flat & 7) * (nwg >> 3) + (flat >> 3);
  const int m0 = (flat / (int)gridDim.x) * 256, n0 = (flat % (int)gridDim.x) * 256;

  const int NSTEP = K / 64;
  f32x16 acc[4][2] = {};

  const u16* As = A + (size_t)(m0 >> 8) * NSTEP * 16384;
  const u16* Bs = B + (size_t)(n0 >> 8) * NSTEP * 16384;

  // prologue: tile 0 full (8 loads, oldest) + {Ah0,Bcol0}(1) (4 loads);
  // vmcnt(4) confirms tile 0, leaves tile-1 P1-group in flight.
  STG_AH(0, 0); STG_AH(0, 1); STG_BC(0, 0); STG_BC(0, 1);
  STG_AH(1, 0); STG_BC(1, 0);
  VMW(4);
  __builtin_amdgcn_s_barrier();

  short8 af[4][4], bf[4];
  for (int t = 0; t < NSTEP; ++t) {
    const int bi = t & 1;
    // ---- P0: column 0 (reads all A + B-col0) ----
    LDA_ALL; LDB(0);
    if (t + 1 < NSTEP) { STG_AH(t + 1, 1); STG_BC(t + 1, 1); }
    MFMA_COL(0);
    __builtin_amdgcn_s_barrier();
    // ---- P1: column 1 (reads B-col1); stage t+2 into disjoint regions ----
    LDB(1);
    if (t + 2 < NSTEP) { STG_AH(t + 2, 0); STG_BC(t + 2, 0); }
    MFMA_COL(1);
    if (t + 2 < NSTEP)
      VMW(4);
    else if (t + 1 < NSTEP)
      VMW(0);
    __builtin_amdgcn_s_barrier();
  }

#pragma unroll
  for (int nf = 0; nf < 2; ++nf) {
    const int col = n0 + wc * 64 + nf * 32 + c5;
    float bval, os;
    if (MODE == 0) {
      const int seg = col >> 11;
      const float* bp = seg == 0 ? bq : (seg == 1 ? bk : bvp);
      bval = bp[col & (DM - 1)];
      os = (seg == 0) ? QSCALE : 1.0f;
    } else {
      bval = bq[col];
      os = 1.0f;
    }
#pragma unroll
    for (int mf = 0; mf < 4; ++mf) {
#pragma unroll
      for (int r = 0; r < 16; ++r) {
        const int row = m0 + wr * 128 + mf * 32 + (r & 3) + 8 * (r >> 2) + 4 * hi;
        const float v = (acc[mf][nf][r] + bval) * os;
        if (MODE == 1)
          ((float*)Cout)[(size_t)row * N + col] = v;
        else
          ((u16*)Cout)[(size_t)row * N + col] = f2bf(v);
      }
    }
  }
}

// Flash attention (round-11 proven version): 8 waves x 32 q, KV tiles of 64,
// K dbuf via gload_lds, V single-buffered write-late (2 barriers/tile),
// swapped QK^T (ds-outer) -> in-register softmax (tree max, cvt_pk +
// permlane32_swap). ctx out in P-layout. Measured: 0 bank conflicts.
__global__ __launch_bounds__(512, 2) void attn(
    const u16* __restrict__ QKV, u16* __restrict__ O) {
  __shared__ u16 smK[2 * 8192];
  __shared__ u16 smV[9216];
  __shared__ float alScr[8 * 32];

  const u16* Qp = QKV;
  const u16* Kp = QKV + DM;
  const u16* Vp = QKV + 2 * DM;

  const int tid = threadIdx.x;
  const int w = tid >> 6, l = tid & 63;
  const int c5 = l & 31, hi = l >> 5;

  int flat = blockIdx.x + ((int)blockIdx.y << 3) + ((int)blockIdx.z << 7);
  flat = (flat & 7) * 64 + (flat >> 3);
  const int qt = flat & 7, h = (flat >> 3) & 15, b = flat >> 7;

  const int q0 = qt * 256 + w * 32;
  const size_t rowb = (size_t)b * SQ;
  const int hoff = h * DKH;

  short8 qf[8];
#pragma unroll
  for (int ds = 0; ds < 8; ++ds)
    qf[ds] = *(const short8*)&Qp[(rowb + q0 + c5) * LD3 + hoff + ds * 16 + hi * 8];

  f32x16 o[4] = {};
  float mrow = -1e30f, lsum = 0.f;

  const int vdg = tid >> 5;
  const int kvp = (tid & 31) * 2;
  u16x8 va, vb;

  {
#pragma unroll
    for (int uu = 0; uu < 2; ++uu) {
      const int u = w * 2 + uu;
      const int row = u * 4 + (l >> 4);
      const int col16 = (l & 15) ^ (row & 15);
      gload16(&Kp[(rowb + row) * LD3 + hoff + col16 * 8], &smK[u * 512]);
    }
    const u16* vp = &Vp[(rowb + kvp) * LD3 + hoff + vdg * 8];
    va = *(const u16x8*)vp;
    vb = *(const u16x8*)(vp + LD3);
#pragma unroll
    for (int i = 0; i < 8; ++i) {
      const int d = vdg * 8 + i;
      *(u32*)&smV[d * 72 + kvp] = (u32)va[i] | ((u32)vb[i] << 16);
    }
  }
  __syncthreads();

  int buf = 0;
  for (int t = 0; t < NT; ++t) {
    const int nb = buf ^ 1;
    if (t + 1 < NT) {
      const size_t kvr = rowb + (size_t)(t + 1) * KT;
#pragma unroll
      for (int uu = 0; uu < 2; ++uu) {
        const int u = w * 2 + uu;
        const int row = u * 4 + (l >> 4);
        const int col16 = (l & 15) ^ (row & 15);
        gload16(&Kp[(kvr + row) * LD3 + hoff + col16 * 8], &smK[nb * 8192 + u * 512]);
      }
      const u16* vp = &Vp[(kvr + kvp) * LD3 + hoff + vdg * 8];
      va = *(const u16x8*)vp;
      vb = *(const u16x8*)(vp + LD3);
    }

    f32x16 s[2] = {};
    __builtin_amdgcn_s_setprio(1);
#pragma unroll
    for (int ds = 0; ds < 8; ++ds) {
#pragma unroll
      for (int ni = 0; ni < 2; ++ni) {
        const int row = ni * 32 + c5;
        const short8 kf = *(const short8*)&smK[buf * 8192 + row * 128 + (((ds << 1) | hi) ^ (row & 15)) * 8];
        s[ni] = __builtin_amdgcn_mfma_f32_32x32x16_bf16(kf, qf[ds], s[ni], 0, 0, 0);
      }
    }
    __builtin_amdgcn_s_setprio(0);

    float mt[16];
#pragma unroll
    for (int i = 0; i < 16; ++i) mt[i] = fmaxf(s[0][i], s[1][i]);
#pragma unroll
    for (int st = 8; st >= 1; st >>= 1)
#pragma unroll
      for (int i = 0; i < st; ++i) mt[i] = fmaxf(mt[i], mt[i + st]);
    i32x2 sw = __builtin_amdgcn_permlane32_swap(__float_as_int(mt[0]), __float_as_int(mt[0]), false, false);
    const float gmax = fmaxf(__int_as_float(sw.x), __int_as_float(sw.y));

    if (__any(gmax > mrow + 10.0f)) {
      const float mn = fmaxf(mrow, gmax);
      const float al = exp2f(mrow - mn);
      mrow = mn;
      lsum *= al;
      alScr[w * 32 + c5] = al;
#pragma unroll
      for (int r = 0; r < 16; ++r) {
        const float av = alScr[w * 32 + (r & 3) + 8 * (r >> 2) + 4 * hi];
#pragma unroll
        for (int dg = 0; dg < 4; ++dg) o[dg][r] *= av;
      }
    }

    float ps0 = 0.f, ps1 = 0.f;
#pragma unroll
    for (int i = 0; i < 16; ++i) {
      const float p0 = exp2f(s[0][i] - mrow);
      const float p1 = exp2f(s[1][i] - mrow);
      s[0][i] = p0; s[1][i] = p1;
      ps0 += p0; ps1 += p1;
    }
    lsum += ps0 + ps1;

    __builtin_amdgcn_s_setprio(1);
#pragma unroll
    for (int ks = 0; ks < 4; ++ks) {
      const int b0_ = (ks & 1) * 8;
      const int ni = ks >> 1;
      const u32 A0 = cvtpk(s[ni][b0_ + 0], s[ni][b0_ + 1]);
      const u32 A1 = cvtpk(s[ni][b0_ + 4], s[ni][b0_ + 5]);
      const u32 B0 = cvtpk(s[ni][b0_ + 2], s[ni][b0_ + 3]);
      const u32 B1 = cvtpk(s[ni][b0_ + 6], s[ni][b0_ + 7]);
      const i32x2 r0 = __builtin_amdgcn_permlane32_swap((int)A0, (int)A1, false, false);
      const i32x2 r1 = __builtin_amdgcn_permlane32_swap((int)B0, (int)B1, false, false);
      u32x4 paw;
      paw.x = (u32)r0.x; paw.y = (u32)r1.x; paw.z = (u32)r0.y; paw.w = (u32)r1.y;
      const short8 pa = *(const short8*)&paw;
#pragma unroll
      for (int dg = 0; dg < 4; ++dg) {
        const int rowd = dg * 32 + c5;
        const short8 vf = *(const short8*)&smV[rowd * 72 + ks * 16 + hi * 8];
        o[dg] = __builtin_amdgcn_mfma_f32_32x32x16_bf16(pa, vf, o[dg], 0, 0, 0);
      }
    }
    __builtin_amdgcn_s_setprio(0);

    __syncthreads();
    if (t + 1 < NT) {
#pragma unroll
      for (int i = 0; i < 8; ++i) {
        const int d = vdg * 8 + i;
        *(u32*)&smV[d * 72 + kvp] = (u32)va[i] | ((u32)vb[i] << 16);
      }
      __syncthreads();
    }
    buf = nb;
  }

  {
    const i32x2 sl = __builtin_amdgcn_permlane32_swap(__float_as_int(lsum), __float_as_int(lsum), false, false);
    const float tot = __int_as_float(sl.x) + __int_as_float(sl.y);
    alScr[w * 32 + c5] = 1.0f / tot;
  }
#pragma unroll
  for (int r = 0; r < 16; ++r) {
    const int qloc = (r & 3) + 8 * (r >> 2) + 4 * hi;
    const float inv = alScr[w * 32 + qloc];
    const int rowg = (int)rowb + q0 + qloc;
#pragma unroll
    for (int dg = 0; dg < 4; ++dg)
      O[paddr16(rowg, hoff + dg * 32 + c5, 32)] = f2bf(o[dg][r] * inv);
  }
}

extern "C" void kernel_launch(void* const* d_in, const int* in_sizes, int n_in,
                              void* d_out, int out_size, void* d_ws, size_t ws_size,
                              hipStream_t stream) {
  const float* x    = (const float*)d_in[0];
  const float* wq_w = (const float*)d_in[1];
  const float* wq_b = (const float*)d_in[2];
  const float* wk_w = (const float*)d_in[3];
  const float* wk_b = (const float*)d_in[4];
  const float* wv_w = (const float*)d_in[5];
  const float* wv_b = (const float*)d_in[6];
  const float* wo_w = (const float*)d_in[7];
  const float* wo_b = (const float*)d_in[8];
  float* out = (float*)d_out;

  u16* p = (u16*)d_ws;
  u16* xb  = p; p += (size_t)NROW * DM;          // x in P-layout, reused as ctx (P)
  u16* wqb = p; p += (size_t)3 * DM * DM;        // wq|wk|wv stacked, P-layout
  u16* wob = p; p += (size_t)DM * DM;            // wo, P-layout
  u16* QKV = p; p += (size_t)NROW * LD3;         // fused [8192][6144] row-major
  u16* ctx = xb;

  cvt_all<<<dim3((NX8 + 4 * NW8) / 256), dim3(256), 0, stream>>>(
      x, wq_w, wk_w, wv_w, wo_w, xb, wqb, wob);

  // fused QKV projection: [8192][2048] @ [6144][2048]^T -> [8192][6144]
  dim3 gg3(3 * DM / 256, NROW / 256);
  gemm8p<0><<<gg3, dim3(512), 0, stream>>>(xb, wqb, wq_b, wk_b, wv_b, QKV,
                                           NROW, 3 * DM, DM);

  attn<<<dim3(SQ / 256, NH, NB), dim3(512), 0, stream>>>(QKV, ctx);

  dim3 ggo(DM / 256, NROW / 256);
  gemm8p<1><<<ggo, dim3(512), 0, stream>>>(ctx, wob, wo_b, nullptr, nullptr, out,
                                           NROW, DM, DM);
}